// Round 7
// baseline (68.039 us; speedup 1.0000x reference)
//
#include <hip/hip_runtime.h>
#include <hip/hip_bf16.h>
#include <cstdint>
#include <cstddef>

typedef __attribute__((ext_vector_type(8))) short bf16x8;
typedef __attribute__((ext_vector_type(4))) float f32x4;
typedef __attribute__((ext_vector_type(4))) unsigned int u32x4;

#define T_DIM 2048
#define C_DIM 1024
#define B_DIM 8
#define NEG_BIG (-3.0e38f)

__device__ __forceinline__ unsigned short f2bf(float f) {
  union { __hip_bfloat16 h; unsigned short u; } cv;
  cv.h = __float2bfloat16(f);
  return cv.u;
}
__device__ __forceinline__ f32x4 mfma16(bf16x8 a, bf16x8 b, f32x4 c) {
  return __builtin_amdgcn_mfma_f32_16x16x32_bf16(a, b, c, 0, 0, 0);
}

// ---------------------------------------------------------------------------
// prep_w: W [1024][64] f32 -> Wt [3][64][1024] bf16 (transposed; Wq scaled 1/8)
// (unchanged)
// ---------------------------------------------------------------------------
__global__ __launch_bounds__(256) void prep_w(
    const float* __restrict__ Wq, const float* __restrict__ Wk,
    const float* __restrict__ Wv, unsigned short* __restrict__ Wt)
{
  const int mtx = blockIdx.x >> 4;
  const int k0  = (blockIdx.x & 15) * 64;
  const float* W = (mtx == 0) ? Wq : ((mtx == 1) ? Wk : Wv);
  const float scale = (mtx == 0) ? 0.125f : 1.0f;
  __shared__ float Ws[64][65];
  const int t = threadIdx.x;
#pragma unroll
  for (int j = 0; j < 4; ++j) {
    int r = (t >> 4) + 16 * j;
    int c = (t & 15) * 4;
    union { float4 f4; float f[4]; } uv;
    uv.f4 = *(const float4*)&W[(size_t)(k0 + r) * 64 + c];
#pragma unroll
    for (int jj = 0; jj < 4; ++jj) Ws[c + jj][r] = uv.f[jj] * scale;
  }
  __syncthreads();
#pragma unroll
  for (int q = 0; q < 2; ++q) {
    int g_ = t + 256 * q;
    int d  = g_ >> 3;
    int ko = (g_ & 7) * 8;
    union { unsigned short u[8]; u32x4 v; } pk;
#pragma unroll
    for (int jj = 0; jj < 8; ++jj) pk.u[jj] = f2bf(Ws[d][ko + jj]);
    *(u32x4*)&Wt[((size_t)mtx * 64 + d) * C_DIM + k0 + ko] = pk.v;
  }
}

// ---------------------------------------------------------------------------
// qkv_proj_mfma: round-5 version (verified ~22 us). Unchanged.
// ---------------------------------------------------------------------------
__global__ __launch_bounds__(256) void qkv_proj_mfma(
    const float* __restrict__ x,
    const unsigned short* __restrict__ Wt,
    const float* __restrict__ bq, const float* __restrict__ bk, const float* __restrict__ bv,
    unsigned short* __restrict__ Qb, unsigned short* __restrict__ Kb,
    unsigned short* __restrict__ VTb)
{
  __shared__ __align__(16) short Xs[64 * 64];
  __shared__ __align__(16) short Ws[3 * 64 * 64];
  __shared__ __align__(16) unsigned short VTs[64 * 72];

  const int tid = threadIdx.x;
  const int wv = tid >> 6, lane = tid & 63, g = lane >> 4, ln15 = lane & 15;
  const size_t m0 = (size_t)blockIdx.x * 64;

  f32x4 acc[4][3];
#pragma unroll
  for (int mt = 0; mt < 4; ++mt)
#pragma unroll
    for (int j = 0; j < 3; ++j) acc[mt][j] = (f32x4){0.f, 0.f, 0.f, 0.f};

  for (int kt = 0; kt < 16; ++kt) {
    __syncthreads();
#pragma unroll
    for (int q = 0; q < 4; ++q) {
      int g_ = tid + 256 * q;
      int r = g_ >> 4, c4 = (g_ & 15) * 4;
      union { float4 f4; float f[4]; } uv;
      uv.f4 = *(const float4*)&x[(m0 + r) * C_DIM + kt * 64 + c4];
      union { unsigned short u[4]; unsigned long long ll; } pk;
#pragma unroll
      for (int jj = 0; jj < 4; ++jj) pk.u[jj] = f2bf(uv.f[jj]);
      *(unsigned long long*)((char*)Xs + r * 128 + ((c4 * 2) ^ ((r & 7) << 4))) = pk.ll;
    }
#pragma unroll
    for (int mt = 0; mt < 3; ++mt)
#pragma unroll
      for (int q = 0; q < 2; ++q) {
        int g_ = tid + 256 * q;
        int d = g_ >> 3, ko = (g_ & 7) * 8;
        u32x4 v = *(const u32x4*)&Wt[((size_t)mt * 64 + d) * C_DIM + kt * 64 + ko];
        *(u32x4*)((char*)Ws + mt * 8192 + d * 128 + ((ko * 2) ^ ((d & 7) << 4))) = v;
      }
    __syncthreads();
#pragma unroll
    for (int kc = 0; kc < 2; ++kc) {
      bf16x8 a[4];
#pragma unroll
      for (int mt = 0; mt < 4; ++mt) {
        int xr = mt * 16 + ln15;
        a[mt] = *(const bf16x8*)((const char*)Xs + xr * 128 + ((kc * 64 + g * 16) ^ ((xr & 7) << 4)));
      }
#pragma unroll
      for (int j = 0; j < 3; ++j) {
        int ntg = wv * 3 + j;
        int mtx = ntg >> 2, nc = (ntg & 3) * 16;
        int wrow = nc + ln15;
        bf16x8 bb = *(const bf16x8*)((const char*)Ws + mtx * 8192 + wrow * 128 + ((kc * 64 + g * 16) ^ ((wrow & 7) << 4)));
#pragma unroll
        for (int mt = 0; mt < 4; ++mt)
          acc[mt][j] = mfma16(a[mt], bb, acc[mt][j]);
      }
    }
  }

  __syncthreads();
#pragma unroll
  for (int j = 0; j < 3; ++j) {
    int ntg = wv * 3 + j;
    int mtx = ntg >> 2, nc = (ntg & 3) * 16;
    if (mtx < 2) {
      const float* bias = (mtx == 0) ? bq : bk;
      unsigned short* Out = (mtx == 0) ? Qb : Kb;
      float bvv = bias[nc + ln15] * ((mtx == 0) ? 0.125f : 1.0f);
#pragma unroll
      for (int mt = 0; mt < 4; ++mt)
#pragma unroll
        for (int i = 0; i < 4; ++i)
          Out[(m0 + mt * 16 + 4 * g + i) * 64 + nc + ln15] = f2bf(acc[mt][j][i] + bvv);
    } else {
      float bvv = bv[nc + ln15];
#pragma unroll
      for (int mt = 0; mt < 4; ++mt)
#pragma unroll
        for (int i = 0; i < 4; ++i)
          VTs[(nc + ln15) * 72 + mt * 16 + 4 * g + i] = f2bf(acc[mt][j][i] + bvv);
    }
  }
  __syncthreads();
  {
    int d = tid >> 2, t8 = (tid & 3) * 16;
    u32x4 v0 = *(const u32x4*)&VTs[d * 72 + t8];
    u32x4 v1 = *(const u32x4*)&VTs[d * 72 + t8 + 8];
    size_t b = m0 >> 11, tloc = m0 & 2047;
    *(u32x4*)&VTb[(b * 64 + d) * T_DIM + tloc + t8] = v0;
    *(u32x4*)&VTb[(b * 64 + d) * T_DIM + tloc + t8 + 8] = v1;
  }
}

// ---------------------------------------------------------------------------
// attn_flash: barrier-free flash attention (round-6 structure).
// ONLY change vs round 6: causal-mask gate compares against r0 (min row),
// not rmax — `s0 + 63 > r0`. Round 6's `> rmax` left up to 48 future keys
// unmasked on the diagonal tile for qt%4 != 3.
// ---------------------------------------------------------------------------
__global__ __launch_bounds__(256) void attn_flash(
    const unsigned short* __restrict__ Qb,   // [B*T][64] (pre-scaled 1/8)
    const unsigned short* __restrict__ Kb,   // [B*T][64]
    const unsigned short* __restrict__ VTb,  // [B][64][T]
    float* __restrict__ out)                 // [B*T][64] f32
{
  __shared__ __align__(16) short Ps[4][16 * 64];   // per-wave P slab, swizzled
  __shared__ __align__(16) float Zs[3][16 * 64];   // merge slabs (waves 1..3)
  __shared__ float Ml[3][16][2];

  const int tid  = threadIdx.x;
  const int wv   = tid >> 6;
  const int lane = tid & 63;
  const int g    = lane >> 4;
  const int ln15 = lane & 15;

  const int qt = 127 - (blockIdx.x >> 3);   // longest first (LPT)
  const int b  = blockIdx.x & 7;
  const int r0 = qt * 16;
  const int ntiles = (qt >> 2) + 1;

  const size_t bT = (size_t)b * T_DIM;

  bf16x8 qa[2];
  {
    const unsigned short* qp = Qb + (bT + r0 + ln15) * 64 + g * 8;
    qa[0] = *(const bf16x8*)qp;
    qa[1] = *(const bf16x8*)(qp + 32);
  }

  f32x4 acc[4];
#pragma unroll
  for (int nt = 0; nt < 4; ++nt) acc[nt] = (f32x4){0.f, 0.f, 0.f, 0.f};
  float m_[4], l_[4];
#pragma unroll
  for (int i = 0; i < 4; ++i) { m_[i] = NEG_BIG; l_[i] = 0.f; }

  char* myP = (char*)Ps[wv];

  for (int it = wv; it < ntiles; it += 4) {
    const int s0 = it * 64;
    // K fragments (direct from L2)
    bf16x8 kf[4][2];
#pragma unroll
    for (int nt = 0; nt < 4; ++nt) {
      const unsigned short* kp = Kb + (bT + s0 + nt * 16 + ln15) * 64 + g * 8;
      kf[nt][0] = *(const bf16x8*)kp;
      kf[nt][1] = *(const bf16x8*)(kp + 32);
    }
    // V fragments (issue early; independent of softmax)
    bf16x8 vf[4][2];
#pragma unroll
    for (int nt = 0; nt < 4; ++nt) {
      const unsigned short* vp = VTb + ((size_t)b * 64 + nt * 16 + ln15) * T_DIM + s0 + g * 8;
      vf[nt][0] = *(const bf16x8*)vp;
      vf[nt][1] = *(const bf16x8*)(vp + 32);
    }
    // QK^T
    f32x4 sfr[4];
#pragma unroll
    for (int nt = 0; nt < 4; ++nt) {
      f32x4 a = (f32x4){0.f, 0.f, 0.f, 0.f};
      a = mfma16(qa[0], kf[nt][0], a);
      a = mfma16(qa[1], kf[nt][1], a);
      sfr[nt] = a;
    }
    // causal mask: tile fully unmasked only if s0+63 <= r0 (min row)
    if (s0 + 63 > r0) {
#pragma unroll
      for (int nt = 0; nt < 4; ++nt) {
        int colg = s0 + nt * 16 + ln15;
#pragma unroll
        for (int i = 0; i < 4; ++i) {
          int rowg = r0 + 4 * g + i;
          if (colg > rowg) sfr[nt][i] = NEG_BIG;
        }
      }
    }
    // online softmax (row = 4g+i; kv across 16 lanes x 4 nt frags)
    float mx[4], corr[4];
#pragma unroll
    for (int i = 0; i < 4; ++i)
      mx[i] = fmaxf(fmaxf(sfr[0][i], sfr[1][i]), fmaxf(sfr[2][i], sfr[3][i]));
#pragma unroll
    for (int i = 0; i < 4; ++i) {
#pragma unroll
      for (int off = 1; off < 16; off <<= 1)
        mx[i] = fmaxf(mx[i], __shfl_xor(mx[i], off));
      float mn = fmaxf(m_[i], mx[i]);
      corr[i] = __expf(m_[i] - mn);
      m_[i] = mn;
    }
#pragma unroll
    for (int nt = 0; nt < 4; ++nt)
#pragma unroll
      for (int i = 0; i < 4; ++i)
        sfr[nt][i] = __expf(sfr[nt][i] - m_[i]);
#pragma unroll
    for (int i = 0; i < 4; ++i) {
      float ps = sfr[0][i] + sfr[1][i] + sfr[2][i] + sfr[3][i];
#pragma unroll
      for (int off = 1; off < 16; off <<= 1)
        ps += __shfl_xor(ps, off);
      l_[i] = l_[i] * corr[i] + ps;
    }
#pragma unroll
    for (int nt = 0; nt < 4; ++nt)
#pragma unroll
      for (int i = 0; i < 4; ++i)
        acc[nt][i] *= corr[i];
    // P -> wave-private LDS (swizzled) -> A-fragments (wave-local, no barrier)
#pragma unroll
    for (int nt = 0; nt < 4; ++nt)
#pragma unroll
      for (int i = 0; i < 4; ++i) {
        int r_ = 4 * g + i;
        *(unsigned short*)(myP + r_ * 128 + ((((nt * 16 + ln15)) * 2) ^ ((r_ & 7) << 4))) = f2bf(sfr[nt][i]);
      }
    bf16x8 pa[2];
#pragma unroll
    for (int kc = 0; kc < 2; ++kc)
      pa[kc] = *(const bf16x8*)(myP + ln15 * 128 + ((kc * 64 + g * 16) ^ ((ln15 & 7) << 4)));
    // PV
#pragma unroll
    for (int nt = 0; nt < 4; ++nt) {
      acc[nt] = mfma16(pa[0], vf[nt][0], acc[nt]);
      acc[nt] = mfma16(pa[1], vf[nt][1], acc[nt]);
    }
  }

  // 4-way merge (single barrier)
  if (wv > 0) {
#pragma unroll
    for (int nt = 0; nt < 4; ++nt)
#pragma unroll
      for (int i = 0; i < 4; ++i)
        Zs[wv - 1][(4 * g + i) * 64 + nt * 16 + ln15] = acc[nt][i];
    if (ln15 == 0) {
#pragma unroll
      for (int i = 0; i < 4; ++i) {
        Ml[wv - 1][4 * g + i][0] = m_[i];
        Ml[wv - 1][4 * g + i][1] = l_[i];
      }
    }
  }
  __syncthreads();
  if (wv == 0) {
    float mm[4], e0[4], ew[3][4], inv[4];
#pragma unroll
    for (int i = 0; i < 4; ++i) {
      mm[i] = m_[i];
#pragma unroll
      for (int w = 0; w < 3; ++w) mm[i] = fmaxf(mm[i], Ml[w][4 * g + i][0]);
      e0[i] = __expf(m_[i] - mm[i]);
      float lsum = l_[i] * e0[i];
#pragma unroll
      for (int w = 0; w < 3; ++w) {
        ew[w][i] = __expf(Ml[w][4 * g + i][0] - mm[i]);
        lsum += Ml[w][4 * g + i][1] * ew[w][i];
      }
      inv[i] = 1.0f / lsum;
    }
    float* ob = out + (bT + r0) * 64;
#pragma unroll
    for (int nt = 0; nt < 4; ++nt)
#pragma unroll
      for (int i = 0; i < 4; ++i) {
        float z = acc[nt][i] * e0[i];
#pragma unroll
        for (int w = 0; w < 3; ++w)
          z += Zs[w][(4 * g + i) * 64 + nt * 16 + ln15] * ew[w][i];
        ob[(size_t)(4 * g + i) * 64 + nt * 16 + ln15] = z * inv[i];
      }
  }
}

// ---------------------------------------------------------------------------
extern "C" void kernel_launch(void* const* d_in, const int* in_sizes, int n_in,
                              void* d_out, int out_size, void* d_ws, size_t ws_size,
                              hipStream_t stream)
{
  const float* x  = (const float*)d_in[0];
  const float* Wq = (const float*)d_in[1];
  const float* bq = (const float*)d_in[2];
  const float* Wk = (const float*)d_in[3];
  const float* bk = (const float*)d_in[4];
  const float* Wv = (const float*)d_in[5];
  const float* bv = (const float*)d_in[6];
  float* out = (float*)d_out;

  char* ws = (char*)d_ws;
  unsigned short* Wt  = (unsigned short*)(ws);                      // 384 KB
  unsigned short* Qb  = (unsigned short*)(ws + (1u << 19));         // 2 MB
  unsigned short* Kb  = (unsigned short*)(ws + (1u << 19) + (1u << 21));
  unsigned short* VTb = (unsigned short*)(ws + (1u << 19) + (2u << 21));

  prep_w<<<48, 256, 0, stream>>>(Wq, Wk, Wv, Wt);
  qkv_proj_mfma<<<256, 256, 0, stream>>>(x, Wt, bq, bk, bv, Qb, Kb, VTb);
  attn_flash<<<1024, 256, 0, stream>>>(Qb, Kb, VTb, out);
}